// Round 7
// baseline (4219.929 us; speedup 1.0000x reference)
//
#include <hip/hip_runtime.h>
#include <hip/hip_bf16.h>
#include <math.h>

#define EDIM   1024
#define TSEQ   512
#define NBATCH 2
#define NHEAD  16
#define HDIM   64
#define NLAYER 24
#define VOCAB  8124
#define DFFDIM 2730
#define DPAD   2752              // 43*64 padded SwiGLU width
#define MTOK   (NBATCH*TSEQ)     // 1024
#define NELEM  (MTOK*EDIM)
#define EPSF   1e-5f
#define SCALEF (1.0f/32.0f)
#define NEGBIG (-1e30f)

typedef __bf16 bf16x8 __attribute__((ext_vector_type(8)));
typedef __bf16 bf16x4 __attribute__((ext_vector_type(4)));
typedef float  f32x4  __attribute__((ext_vector_type(4)));

#define MFMA(a, b, c) __builtin_amdgcn_mfma_f32_16x16x32_bf16((a), (b), (c), 0, 0, 0)

__device__ __forceinline__ void gl_lds16(const __bf16* g, __bf16* l) {
  __builtin_amdgcn_global_load_lds(
      (const __attribute__((address_space(1))) void*)g,
      (__attribute__((address_space(3))) void*)l, 16, 0, 0);
}
template <int N> __device__ __forceinline__ void vmwait() {
  asm volatile("s_waitcnt vmcnt(%0)" :: "n"(N) : "memory");
}
__device__ __forceinline__ void lgkm_barrier() {
  asm volatile("s_waitcnt lgkmcnt(0)" ::: "memory");
  __builtin_amdgcn_s_barrier();
}

// ---------------------------------------------------------------- embedding+PE
__global__ __launch_bounds__(256) void k_embed(const int* __restrict__ tok,
                                               const float* __restrict__ emb,
                                               float* __restrict__ x) {
  const int bt = blockIdx.x;
  const int t  = bt & (TSEQ - 1);
  const int tk = tok[bt];
  const float* er = emb + (size_t)tk * EDIM;
  float* xr = x + (size_t)bt * EDIM;
  for (int e = threadIdx.x * 4; e < EDIM; e += 256 * 4) {
    float4 v = *(const float4*)(er + e);
    float vv[4] = {v.x, v.y, v.z, v.w};
    float ou[4];
#pragma unroll
    for (int j = 0; j < 4; ++j) {
      int ee = e + j;
      int i2 = ee & ~1;
      float freq = expf(-(float)i2 * (9.210340371976184f / 1024.0f));
      float ang  = (float)t * freq;
      ou[j] = vv[j] + ((ee & 1) ? cosf(ang) : sinf(ang));
    }
    *(float4*)(xr + e) = make_float4(ou[0], ou[1], ou[2], ou[3]);
  }
}

// ------------------------------------------------- RMS reduce (+fold np partials)
__global__ __launch_bounds__(256) void k_red1f(float* __restrict__ x,
                                               const float* __restrict__ pb,
                                               int np,
                                               const float* __restrict__ bias,
                                               float* __restrict__ part) {
  float s = 0.f;
  const bool fold = (pb != nullptr);
  for (int i = (blockIdx.x * 256 + threadIdx.x) * 4; i < NELEM; i += 256 * 256 * 4) {
    float4 v = *(const float4*)(x + i);
    if (fold) {
      for (int z = 0; z < np; ++z) {
        float4 a = *(const float4*)(pb + (size_t)z * NELEM + i);
        v.x += a.x; v.y += a.y; v.z += a.z; v.w += a.w;
      }
      float4 c = *(const float4*)(bias + (i & (EDIM - 1)));
      v.x += c.x; v.y += c.y; v.z += c.z; v.w += c.w;
      *(float4*)(x + i) = v;
    }
    s += v.x * v.x + v.y * v.y + v.z * v.z + v.w * v.w;
  }
#pragma unroll
  for (int o = 32; o > 0; o >>= 1) s += __shfl_down(s, o);
  __shared__ float sm[4];
  if ((threadIdx.x & 63) == 0) sm[threadIdx.x >> 6] = s;
  __syncthreads();
  if (threadIdx.x == 0) part[blockIdx.x] = sm[0] + sm[1] + sm[2] + sm[3];
}

// ------------------------------------------------- weight convert + transpose
// src [K][N] f32 -> dst [Npad][Kpad] bf16, optionally row-scaled by gk[k]
// (RMS gain folded into weights; the runtime RMS scalar is applied in the
//  GEMM epilogue instead — kills the separate rms-apply kernel.)
__device__ __forceinline__ void conv_tile(const float* __restrict__ src,
                                          const float* __restrict__ gk,
                                          __bf16* __restrict__ dst,
                                          int K, int N, int Kpad, int tk, int tn) {
  __shared__ float st[64][65];
  const int k0 = tk << 6, n0 = tn << 6;
  const int tid = threadIdx.x;
  {
    const int r0 = tid >> 4, c4 = (tid & 15) << 2;
#pragma unroll
    for (int i = 0; i < 4; ++i) {
      const int r = r0 + i * 16;
      const int k = k0 + r;
      float4 v = make_float4(0.f, 0.f, 0.f, 0.f);
      if (k < K) {
        const float* sp = src + (size_t)k * N + n0 + c4;
        if (n0 + c4 + 3 < N) v = *(const float4*)sp;
        else {
          if (n0 + c4 + 0 < N) v.x = sp[0];
          if (n0 + c4 + 1 < N) v.y = sp[1];
          if (n0 + c4 + 2 < N) v.z = sp[2];
          if (n0 + c4 + 3 < N) v.w = sp[3];
        }
        if (gk) {
          const float gv = gk[k];
          v.x *= gv; v.y *= gv; v.z *= gv; v.w *= gv;
        }
      }
      st[r][c4 + 0] = v.x; st[r][c4 + 1] = v.y; st[r][c4 + 2] = v.z; st[r][c4 + 3] = v.w;
    }
  }
  __syncthreads();
  {
    const int nl0 = tid >> 3, c8 = (tid & 7) << 3;
#pragma unroll
    for (int i = 0; i < 2; ++i) {
      const int nl = nl0 + i * 32;
      bf16x8 o = {(__bf16)st[c8 + 0][nl], (__bf16)st[c8 + 1][nl],
                  (__bf16)st[c8 + 2][nl], (__bf16)st[c8 + 3][nl],
                  (__bf16)st[c8 + 4][nl], (__bf16)st[c8 + 5][nl],
                  (__bf16)st[c8 + 6][nl], (__bf16)st[c8 + 7][nl]};
      *(bf16x8*)&dst[(size_t)(n0 + nl) * Kpad + k0 + c8] = o;
    }
  }
}

__global__ __launch_bounds__(256) void k_convAll(const float* __restrict__ Wqkv,
                                                 const float* __restrict__ Wo,
                                                 const float* __restrict__ W1,
                                                 const float* __restrict__ W3,
                                                 const float* __restrict__ W2w,
                                                 const float* __restrict__ g_mha,
                                                 const float* __restrict__ g_ff,
                                                 __bf16* qkvT, __bf16* woT,
                                                 __bf16* w1T, __bf16* w3T, __bf16* w2T) {
  int b = blockIdx.x;
  const int l = b / 3088; b -= l * 3088;
  if (b < 768) {
    conv_tile(Wqkv + (size_t)l * 1024 * 3072, g_mha + (size_t)l * EDIM,
              qkvT + (size_t)l * 3072 * 1024, 1024, 3072, 1024, b / 48, b % 48);
  } else if (b < 1024) {
    int t = b - 768;
    conv_tile(Wo + (size_t)l * 1024 * 1024, nullptr,
              woT + (size_t)l * 1024 * 1024, 1024, 1024, 1024, t / 16, t % 16);
  } else if (b < 1712) {
    int t = b - 1024;
    conv_tile(W1 + (size_t)l * 1024 * DFFDIM, g_ff + (size_t)l * EDIM,
              w1T + (size_t)l * DPAD * 1024, 1024, DFFDIM, 1024, t / 43, t % 43);
  } else if (b < 2400) {
    int t = b - 1712;
    conv_tile(W3 + (size_t)l * 1024 * DFFDIM, g_ff + (size_t)l * EDIM,
              w3T + (size_t)l * DPAD * 1024, 1024, DFFDIM, 1024, t / 43, t % 43);
  } else {
    int t = b - 2400;
    conv_tile(W2w + (size_t)l * DFFDIM * 1024, nullptr,
              w2T + (size_t)l * 1024 * DPAD, DFFDIM, 1024, DPAD, t / 16, t % 16);
  }
}

__global__ __launch_bounds__(256) void k_convH(const float* __restrict__ Wout,
                                               const float* __restrict__ g_final,
                                               __bf16* __restrict__ WoutT) {
  conv_tile(Wout, g_final, WoutT, 1024, VOCAB, 1024, blockIdx.x >> 7, blockIdx.x & 127);
}

// ================================================================ MFMA GEMM
// BM=128, BN in {64,128}; BK=64; 4 waves, wave tile 64 x BN/2.
// FUSE=1: A comes from f32 x (reg-staged, cvt->ds_write, XOR-swizzled rows);
//         epilogue multiplies acc by RMS scalar sc (re-reduced from part[256]).
// FUSE=0: A bf16 via global_load_lds (lane-linear dest), counted vmcnt.
// MODE: 0=qkv scatter  1=split-K partial (f32)  2=SwiGLU dual  3=head
template <int BN, int MODE, int FUSE>
__global__ __launch_bounds__(256) void mm(
    const __bf16* __restrict__ A, const float* __restrict__ Af,
    const __bf16* __restrict__ B0w, const __bf16* __restrict__ B1w,
    const float* __restrict__ bias0, const float* __restrict__ bias1,
    const float* __restrict__ part,
    float* __restrict__ po, __bf16* __restrict__ ob,
    __bf16* __restrict__ qout, __bf16* __restrict__ kout, __bf16* __restrict__ vout,
    int N, int lda, int ldb, int Ktot) {
  constexpr int DUAL = (MODE == 2) ? 2 : 1;
  constexpr int FN = BN / 32;
  constexpr int BL = (BN == 128) ? 4 : 2 * DUAL;   // B gl_lds per thread/stage
  __shared__ __bf16 As[2][8][128][8];
  __shared__ __bf16 Bs[2][DUAL][8][BN][8];
  const int tid = threadIdx.x, lane = tid & 63, wave = tid >> 6;
  const int m0 = blockIdx.y << 7, n0 = blockIdx.x * BN;
  const int wm0 = (wave >> 1) * 64, wn0 = (wave & 1) * (BN / 2);
  const int lr = lane & 15, kh = lane >> 4;

  const int ktiles = Ktot >> 6;
  const int nt0 = (ktiles + gridDim.z - 1) / gridDim.z;
  const int tbeg = blockIdx.z * nt0;
  const int tend = (ktiles < tbeg + nt0) ? ktiles : (tbeg + nt0);
  const int nt = tend - tbeg;

  f32x4 acc[DUAL][4][FN];
#pragma unroll
  for (int d = 0; d < DUAL; ++d)
#pragma unroll
    for (int mi = 0; mi < 4; ++mi)
#pragma unroll
      for (int fn = 0; fn < FN; ++fn) acc[d][mi][fn] = (f32x4){0.f, 0.f, 0.f, 0.f};

  float4 ar[4][2];
  auto LOADA = [&](int t) {              // FUSE: coalesced f32 loads
    const int k0 = (tbeg + t) << 6;
#pragma unroll
    for (int i = 0; i < 4; ++i) {
      const int d = i * 256 + tid;
      const int row = d >> 3, kb = d & 7;
      const float* ap = Af + (size_t)(m0 + row) * lda + k0 + kb * 8;
      ar[i][0] = *(const float4*)ap; ar[i][1] = *(const float4*)(ap + 4);
    }
  };
  auto DSWA = [&](int buf) {             // cvt + XOR-swizzled ds_write_b128
#pragma unroll
    for (int i = 0; i < 4; ++i) {
      const int d = i * 256 + tid;
      const int row = d >> 3, kb = d & 7;
      float4 a = ar[i][0], b = ar[i][1];
      bf16x8 w = {(__bf16)a.x, (__bf16)a.y, (__bf16)a.z, (__bf16)a.w,
                  (__bf16)b.x, (__bf16)b.y, (__bf16)b.z, (__bf16)b.w};
      *(bf16x8*)&As[buf][kb][row ^ kb][0] = w;
    }
  };
  auto STAGEA_G = [&](int buf, int t) {  // FUSE=0: gl_lds, lane-linear dest
    const int k0 = (tbeg + t) << 6;
#pragma unroll
    for (int i = 0; i < 4; ++i) {
      const int d = i * 256 + tid;
      gl_lds16(A + (size_t)(m0 + (d & 127)) * lda + k0 + (d >> 7) * 8,
               &As[buf][d >> 7][d & 127][0]);
    }
  };
  auto STAGEB = [&](int buf, int t) {
    const int k0 = (tbeg + t) << 6;
    if (BN == 128) {
#pragma unroll
      for (int i = 0; i < 4; ++i) {
        const int d = i * 256 + tid;
        gl_lds16(B0w + (size_t)(n0 + (d & 127)) * ldb + k0 + (d >> 7) * 8,
                 &Bs[buf][0][d >> 7][d & 127][0]);
      }
    } else {
#pragma unroll
      for (int i = 0; i < 2; ++i) {
        const int d = i * 256 + tid;
        gl_lds16(B0w + (size_t)(n0 + (d & 63)) * ldb + k0 + (d >> 6) * 8,
                 &Bs[buf][0][d >> 6][d & 63][0]);
      }
      if (DUAL == 2) {
#pragma unroll
        for (int i = 0; i < 2; ++i) {
          const int d = i * 256 + tid;
          gl_lds16(B1w + (size_t)(n0 + (d & 63)) * ldb + k0 + (d >> 6) * 8,
                   &Bs[buf][DUAL - 1][d >> 6][d & 63][0]);
        }
      }
    }
  };
  auto COMP = [&](int buf) {
#pragma unroll
    for (int ks = 0; ks < 2; ++ks) {
      const int kidx = ks * 4 + kh;
      bf16x8 af[4];
#pragma unroll
      for (int mi = 0; mi < 4; ++mi) {
        const int r = wm0 + mi * 16 + lr;
        af[mi] = *(const bf16x8*)&As[buf][kidx][FUSE ? (r ^ kidx) : r][0];
      }
#pragma unroll
      for (int d = 0; d < DUAL; ++d)
#pragma unroll
        for (int fn = 0; fn < FN; ++fn) {
          bf16x8 bfr = *(const bf16x8*)&Bs[buf][d][kidx][wn0 + fn * 16 + lr][0];
#pragma unroll
          for (int mi = 0; mi < 4; ++mi)
            acc[d][mi][fn] = MFMA(af[mi], bfr, acc[d][mi][fn]);
        }
    }
  };

  int cur = 0;
  if (FUSE) {
    LOADA(0); STAGEB(0, 0); DSWA(0);
    asm volatile("s_waitcnt lgkmcnt(0)" ::: "memory");
    vmwait<0>(); __builtin_amdgcn_s_barrier();
    for (int t = 0; t < nt - 1; ++t) {
      LOADA(t + 1);                 // issue early (T14): hides under COMP
      STAGEB(cur ^ 1, t + 1);       // gl_lds into the idle buffer
      COMP(cur);
      DSWA(cur ^ 1);                // compiler waits A-regs here, post-COMP
      asm volatile("s_waitcnt lgkmcnt(0)" ::: "memory");
      vmwait<0>(); __builtin_amdgcn_s_barrier();
      cur ^= 1;
    }
    COMP(cur);
  } else {
    STAGEA_G(0, 0); STAGEB(0, 0);
    for (int t = 0; t < nt - 1; ++t) {
      STAGEA_G(cur ^ 1, t + 1); STAGEB(cur ^ 1, t + 1);
      vmwait<4 + BL>();             // own tile-t loads retired, next in flight
      __builtin_amdgcn_s_barrier();
      COMP(cur);
      __builtin_amdgcn_s_barrier();
      cur ^= 1;
    }
    vmwait<0>(); __builtin_amdgcn_s_barrier();
    COMP(cur);
  }

  // RMS scalar for FUSE modes
  float sc = 1.0f;
  if (FUSE) {
    __shared__ float smr[4];
    float s = part[tid];
#pragma unroll
    for (int o = 32; o > 0; o >>= 1) s += __shfl_down(s, o);
    if ((tid & 63) == 0) smr[tid >> 6] = s;
    __syncthreads();
    sc = 1.0f / sqrtf((smr[0] + smr[1] + smr[2] + smr[3]) / (float)NELEM + EPSF);
  }

#pragma unroll
  for (int mi = 0; mi < 4; ++mi)
#pragma unroll
    for (int fn = 0; fn < FN; ++fn) {
      const int col = n0 + wn0 + fn * 16 + lr;
      if (MODE == 0) {
        const float bs = bias0[col];
        const int h = col / (3 * HDIM);
        const int rsel = (col >> 6) % 3;
        const int s2 = col & (HDIM - 1);
#pragma unroll
        for (int j = 0; j < 4; ++j) {
          const int row = m0 + wm0 + mi * 16 + (kh << 2) + j;
          const int b = row >> 9, t = row & (TSEQ - 1);
          const float v = acc[0][mi][fn][j] * sc + bs;
          if (rsel == 0)      qout[((size_t)(b * NHEAD + h) * TSEQ + t) * HDIM + s2] = (__bf16)v;
          else if (rsel == 1) kout[((size_t)(b * NHEAD + h) * TSEQ + t) * HDIM + s2] = (__bf16)v;
          else                vout[((size_t)(b * NHEAD + h) * HDIM + s2) * TSEQ + t] = (__bf16)v;
        }
      } else if (MODE == 1) {
        float* pz = po + (size_t)blockIdx.z * NELEM;
#pragma unroll
        for (int j = 0; j < 4; ++j) {
          const int row = m0 + wm0 + mi * 16 + (kh << 2) + j;
          pz[(size_t)row * EDIM + col] = acc[0][mi][fn][j];
        }
      } else if (MODE == 2) {
        const bool ok = col < N;
        const float bb1 = ok ? bias0[col] : 0.f;
        const float bb3 = ok ? bias1[col] : 0.f;
#pragma unroll
        for (int j = 0; j < 4; ++j) {
          const int row = m0 + wm0 + mi * 16 + (kh << 2) + j;
          float v = 0.f;
          if (ok) {
            const float a1v = acc[0][mi][fn][j] * sc + bb1;
            const float a3v = acc[DUAL - 1][mi][fn][j] * sc + bb3;
            v = a1v * (1.0f / (1.0f + __expf(-a1v))) * a3v;
          }
          ob[(size_t)row * DPAD + col] = (__bf16)v;
        }
      } else {  // MODE 3
        if (col < N) {
          const float bs = bias0[col];
#pragma unroll
          for (int j = 0; j < 4; ++j) {
            const int row = m0 + wm0 + mi * 16 + (kh << 2) + j;
            po[(size_t)row * N + col] = acc[0][mi][fn][j] * sc + bs;
          }
        }
      }
    }
}

// ------------------------------------------------- flash attention (bf16 in)
__global__ __launch_bounds__(256) void k_flash(const __bf16* __restrict__ qbuf,
                                               const __bf16* __restrict__ kbuf,
                                               const __bf16* __restrict__ vbufT,
                                               __bf16* __restrict__ y2) {
  const int qt = blockIdx.x, bh = blockIdx.y;
  const int b = bh >> 4, h = bh & 15;
  const int m0 = qt << 6;
  const __bf16* qp = qbuf  + (size_t)bh * TSEQ * HDIM;
  const __bf16* kp = kbuf  + (size_t)bh * TSEQ * HDIM;
  const __bf16* vp = vbufT + (size_t)bh * HDIM * TSEQ;   // [s][t]
  __shared__ __bf16 Qs[8][64][8], Ks[2][8][64][8], Vs[2][8][64][8], Ps[8][64][8];
  __shared__ float wmax[2][64], wsum[2][64];
  const int tid = threadIdx.x, lane = tid & 63, wave = tid >> 6;
  const int wm = (wave >> 1) << 5, wn = (wave & 1) << 5;
  const int lr = lane & 15, kh = lane >> 4;

  auto STAGE_KV = [&](int kt2, int buf) {
    const int n0s = kt2 << 6;
#pragma unroll
    for (int i = 0; i < 2; ++i) {
      const int d = i * 256 + tid;
      const int kb2 = d >> 6, row = d & 63;
      gl_lds16(kp + (size_t)(n0s + row) * HDIM + kb2 * 8, &Ks[buf][kb2][row][0]);
      gl_lds16(vp + (size_t)row * TSEQ + n0s + kb2 * 8, &Vs[buf][kb2][row][0]);
    }
  };

#pragma unroll
  for (int i = 0; i < 2; ++i) {
    const int d = i * 256 + tid;
    const int kb2 = d >> 6, row = d & 63;
    gl_lds16(qp + (size_t)(m0 + row) * HDIM + kb2 * 8, &Qs[kb2][row][0]);
  }
  STAGE_KV(0, 0);

  float m_[2][4], l_[2][4];
#pragma unroll
  for (int mi = 0; mi < 2; ++mi)
#pragma unroll
    for (int j = 0; j < 4; ++j) { m_[mi][j] = NEGBIG; l_[mi][j] = 0.f; }
  f32x4 o00 = {0,0,0,0}, o01 = {0,0,0,0}, o10 = {0,0,0,0}, o11 = {0,0,0,0};

  int cur = 0;
  for (int kt = 0; kt <= qt; ++kt) {
    const int n0 = kt << 6;
    if (kt < qt) {
      STAGE_KV(kt + 1, cur ^ 1);
      vmwait<4>();
    } else {
      vmwait<0>();
    }
    __builtin_amdgcn_s_barrier();

    f32x4 s00 = {0,0,0,0}, s01 = {0,0,0,0}, s10 = {0,0,0,0}, s11 = {0,0,0,0};
#pragma unroll
    for (int ks = 0; ks < 2; ++ks) {
      const int kidx = ks * 4 + kh;
      bf16x8 a0 = *(const bf16x8*)&Qs[kidx][wm + lr][0];
      bf16x8 a1 = *(const bf16x8*)&Qs[kidx][wm + 16 + lr][0];
      bf16x8 b0 = *(const bf16x8*)&Ks[cur][kidx][wn + lr][0];
      bf16x8 b1 = *(const bf16x8*)&Ks[cur][kidx][wn + 16 + lr][0];
      s00 = MFMA(a0, b0, s00); s01 = MFMA(a0, b1, s01);
      s10 = MFMA(a1, b0, s10); s11 = MFMA(a1, b1, s11);
    }
    float pv_[2][2][4];
#pragma unroll
    for (int mi = 0; mi < 2; ++mi)
#pragma unroll
      for (int j = 0; j < 4; ++j) {
        const int grow = m0 + wm + mi * 16 + (kh << 2) + j;
        float best = NEGBIG;
#pragma unroll
        for (int ni = 0; ni < 2; ++ni) {
          f32x4 sfr = (mi == 0) ? (ni == 0 ? s00 : s01) : (ni == 0 ? s10 : s11);
          const int gcol = n0 + wn + ni * 16 + lr;
          float t = sfr[j] * SCALEF;
          if (gcol > grow) t = NEGBIG;
          pv_[mi][ni][j] = t;
          best = fmaxf(best, t);
        }
        float v = best;
        v = fmaxf(v, __shfl_xor(v, 1)); v = fmaxf(v, __shfl_xor(v, 2));
        v = fmaxf(v, __shfl_xor(v, 4)); v = fmaxf(v, __shfl_xor(v, 8));
        wmax[wave & 1][wm + mi * 16 + (kh << 2) + j] = v;
      }
    lgkm_barrier();

    float alpha[2][4];
#pragma unroll
    for (int mi = 0; mi < 2; ++mi)
#pragma unroll
      for (int j = 0; j < 4; ++j) {
        const int rl = wm + mi * 16 + (kh << 2) + j;
        const float tmax = fmaxf(wmax[0][rl], wmax[1][rl]);
        const float mn = fmaxf(m_[mi][j], tmax);
        alpha[mi][j] = __expf(m_[mi][j] - mn);
        m_[mi][j] = mn;
        float rs = 0.f;
#pragma unroll
        for (int ni = 0; ni < 2; ++ni) {
          const float p = __expf(pv_[mi][ni][j] - mn);
          pv_[mi][ni][j] = p;
          rs += p;
        }
        rs += __shfl_xor(rs, 1); rs += __shfl_xor(rs, 2);
        rs += __shfl_xor(rs, 4); rs += __shfl_xor(rs, 8);
        wsum[wave & 1][rl] = rs;
      }
#pragma unroll
    for (int mi = 0; mi < 2; ++mi)
#pragma unroll
      for (int ni = 0; ni < 2; ++ni)
#pragma unroll
        for (int j = 0; j < 4; ++j) {
          const int prow = wm + mi * 16 + (kh << 2) + j;
          const int pcol = wn + ni * 16 + lr;
          Ps[pcol >> 3][prow][pcol & 7] = (__bf16)pv_[mi][ni][j];
        }
    lgkm_barrier();

#pragma unroll
    for (int mi = 0; mi < 2; ++mi)
#pragma unroll
      for (int j = 0; j < 4; ++j) {
        const int rl = wm + mi * 16 + (kh << 2) + j;
        l_[mi][j] = l_[mi][j] * alpha[mi][j] + wsum[0][rl] + wsum[1][rl];
      }
#pragma unroll
    for (int j = 0; j < 4; ++j) {
      o00[j] *= alpha[0][j]; o01[j] *= alpha[0][j];
      o10[j] *= alpha[1][j]; o11[j] *= alpha[1][j];
    }
#pragma unroll
    for (int ks = 0; ks < 2; ++ks) {
      const int kidx = ks * 4 + kh;
      bf16x8 a0 = *(const bf16x8*)&Ps[kidx][wm + lr][0];
      bf16x8 a1 = *(const bf16x8*)&Ps[kidx][wm + 16 + lr][0];
      bf16x8 b0 = *(const bf16x8*)&Vs[cur][kidx][wn + lr][0];
      bf16x8 b1 = *(const bf16x8*)&Vs[cur][kidx][wn + 16 + lr][0];
      o00 = MFMA(a0, b0, o00); o01 = MFMA(a0, b1, o01);
      o10 = MFMA(a1, b0, o10); o11 = MFMA(a1, b1, o11);
    }
    __builtin_amdgcn_s_barrier();
    cur ^= 1;
  }

#pragma unroll
  for (int mi = 0; mi < 2; ++mi)
#pragma unroll
    for (int ni = 0; ni < 2; ++ni) {
      f32x4 oo = (mi == 0) ? (ni == 0 ? o00 : o01) : (ni == 0 ? o10 : o11);
      const int col = wn + ni * 16 + lr;
#pragma unroll
      for (int j = 0; j < 4; ++j) {
        const int row = m0 + wm + mi * 16 + (kh << 2) + j;
        y2[((size_t)(b * TSEQ) + row) * EDIM + h * HDIM + col] = (__bf16)(oo[j] / l_[mi][j]);
      }
    }
}

// ---------------------------------------------------------------- launcher
extern "C" void kernel_launch(void* const* d_in, const int* in_sizes, int n_in,
                              void* d_out, int out_size, void* d_ws, size_t ws_size,
                              hipStream_t stream) {
  const int*   tokens  = (const int*)d_in[0];
  const float* emb     = (const float*)d_in[1];
  const float* Wqkv    = (const float*)d_in[2];
  const float* bqkv    = (const float*)d_in[3];
  const float* Wo      = (const float*)d_in[4];
  const float* bo      = (const float*)d_in[5];
  const float* W1      = (const float*)d_in[6];
  const float* b1      = (const float*)d_in[7];
  const float* W3      = (const float*)d_in[8];
  const float* b3      = (const float*)d_in[9];
  const float* W2w     = (const float*)d_in[10];
  const float* b2      = (const float*)d_in[11];
  const float* g_mha   = (const float*)d_in[12];
  const float* g_ff    = (const float*)d_in[13];
  const float* g_final = (const float*)d_in[14];
  const float* Wout    = (const float*)d_in[15];
  const float* bout    = (const float*)d_in[16];
  float* out = (float*)d_out;

  char* base = (char*)d_ws;
  size_t off = 0;
  auto alloc = [&](size_t bytes) { char* p = base + off; off = (off + bytes + 255) & ~(size_t)255; return p; };
  float*  x    = (float*)alloc(4u << 20);
  float*  part = (float*)alloc(2048);
  __bf16* qbf  = (__bf16*)alloc(2u << 20);
  __bf16* kbf  = (__bf16*)alloc(2u << 20);
  __bf16* vbT  = (__bf16*)alloc(2u << 20);
  __bf16* y2bf = (__bf16*)alloc(2u << 20);
  __bf16* ubf  = (__bf16*)alloc((size_t)MTOK * DPAD * 2);
  float*  pbuf = (float*)alloc((size_t)2 * NELEM * 4);
  __bf16* WoutT = (__bf16*)alloc((size_t)8192 * 1024 * 2);
  __bf16* qkvT = (__bf16*)alloc((size_t)NLAYER * 3072 * 1024 * 2);
  __bf16* woT  = (__bf16*)alloc((size_t)NLAYER * 1024 * 1024 * 2);
  __bf16* w1T  = (__bf16*)alloc((size_t)NLAYER * DPAD * 1024 * 2);
  __bf16* w3T  = (__bf16*)alloc((size_t)NLAYER * DPAD * 1024 * 2);
  __bf16* w2T  = (__bf16*)alloc((size_t)NLAYER * 1024 * DPAD * 2);

  k_embed<<<MTOK, 256, 0, stream>>>(tokens, emb, x);
  k_convAll<<<NLAYER * 3088, 256, 0, stream>>>(Wqkv, Wo, W1, W3, W2w,
                                               g_mha, g_ff,
                                               qkvT, woT, w1T, w3T, w2T);
  k_convH<<<2048, 256, 0, stream>>>(Wout, g_final, WoutT);

  const float* pend_bias = nullptr;
  for (int l = 0; l < NLAYER; ++l) {
    // --- MHA ---
    k_red1f<<<256, 256, 0, stream>>>(x, pend_bias ? pbuf : nullptr, 2, pend_bias, part);
    mm<64, 0, 1><<<dim3(48, 8, 1), 256, 0, stream>>>(
        nullptr, x, qkvT + (size_t)l * 3072 * 1024, nullptr,
        bqkv + (size_t)l * 3 * EDIM, nullptr, part,
        nullptr, nullptr, qbf, kbf, vbT, 3072, EDIM, 1024, 1024);
    k_flash<<<dim3(8, 32), 256, 0, stream>>>(qbf, kbf, vbT, y2bf);
    mm<64, 1, 0><<<dim3(16, 8, 2), 256, 0, stream>>>(
        y2bf, nullptr, woT + (size_t)l * 1024 * 1024, nullptr,
        nullptr, nullptr, nullptr,
        pbuf, nullptr, nullptr, nullptr, nullptr, 1024, 1024, 1024, 1024);
    // --- SwiGLU FFN ---
    k_red1f<<<256, 256, 0, stream>>>(x, pbuf, 2, bo + (size_t)l * EDIM, part);
    mm<64, 2, 1><<<dim3(43, 8, 1), 256, 0, stream>>>(
        nullptr, x, w1T + (size_t)l * DPAD * 1024, w3T + (size_t)l * DPAD * 1024,
        b1 + (size_t)l * DFFDIM, b3 + (size_t)l * DFFDIM, part,
        nullptr, ubf, nullptr, nullptr, nullptr, DFFDIM, EDIM, 1024, 1024);
    mm<64, 1, 0><<<dim3(16, 8, 2), 256, 0, stream>>>(
        ubf, nullptr, w2T + (size_t)l * 1024 * DPAD, nullptr,
        nullptr, nullptr, nullptr,
        pbuf, nullptr, nullptr, nullptr, nullptr, 1024, DPAD, DPAD, DPAD);
    pend_bias = b2 + (size_t)l * EDIM;
  }

  // --- final RMS + vocab head ---
  k_red1f<<<256, 256, 0, stream>>>(x, pbuf, 2, pend_bias, part);
  mm<128, 3, 1><<<dim3(64, 8, 1), 256, 0, stream>>>(
      nullptr, x, WoutT, nullptr, bout, nullptr, part,
      out, nullptr, nullptr, nullptr, nullptr, VOCAB, EDIM, 1024, 1024);
}

// Round 8
// 3961.046 us; speedup vs baseline: 1.0654x; 1.0654x over previous
//
#include <hip/hip_runtime.h>
#include <hip/hip_bf16.h>
#include <math.h>

#define EDIM   1024
#define TSEQ   512
#define NBATCH 2
#define NHEAD  16
#define HDIM   64
#define NLAYER 24
#define VOCAB  8124
#define DFFDIM 2730
#define DPAD   2752              // 43*64 padded SwiGLU width
#define MTOK   (NBATCH*TSEQ)     // 1024
#define NELEM  (MTOK*EDIM)
#define EPSF   1e-5f
#define SCALEF (1.0f/32.0f)
#define NEGBIG (-1e30f)

typedef __bf16 bf16x8 __attribute__((ext_vector_type(8)));
typedef __bf16 bf16x4 __attribute__((ext_vector_type(4)));
typedef float  f32x4  __attribute__((ext_vector_type(4)));

#define MFMA(a, b, c) __builtin_amdgcn_mfma_f32_16x16x32_bf16((a), (b), (c), 0, 0, 0)

__device__ __forceinline__ void gl_lds16(const __bf16* g, __bf16* l) {
  __builtin_amdgcn_global_load_lds(
      (const __attribute__((address_space(1))) void*)g,
      (__attribute__((address_space(3))) void*)l, 16, 0, 0);
}
template <int N> __device__ __forceinline__ void vmwait() {
  asm volatile("s_waitcnt vmcnt(%0)" :: "n"(N) : "memory");
}
__device__ __forceinline__ void lgkm_barrier() {
  asm volatile("s_waitcnt lgkmcnt(0)" ::: "memory");
  __builtin_amdgcn_s_barrier();
}

// ---------------------------------------------------------------- embedding+PE
__global__ __launch_bounds__(256) void k_embed(const int* __restrict__ tok,
                                               const float* __restrict__ emb,
                                               float* __restrict__ x) {
  const int bt = blockIdx.x;
  const int t  = bt & (TSEQ - 1);
  const int tk = tok[bt];
  const float* er = emb + (size_t)tk * EDIM;
  float* xr = x + (size_t)bt * EDIM;
  for (int e = threadIdx.x * 4; e < EDIM; e += 256 * 4) {
    float4 v = *(const float4*)(er + e);
    float vv[4] = {v.x, v.y, v.z, v.w};
    float ou[4];
#pragma unroll
    for (int j = 0; j < 4; ++j) {
      int ee = e + j;
      int i2 = ee & ~1;
      float freq = expf(-(float)i2 * (9.210340371976184f / 1024.0f));
      float ang  = (float)t * freq;
      ou[j] = vv[j] + ((ee & 1) ? cosf(ang) : sinf(ang));
    }
    *(float4*)(xr + e) = make_float4(ou[0], ou[1], ou[2], ou[3]);
  }
}

// ------------------------------------------------- RMS reduce (+fold np partials)
__global__ __launch_bounds__(256) void k_red1f(float* __restrict__ x,
                                               const float* __restrict__ pb,
                                               int np,
                                               const float* __restrict__ bias,
                                               float* __restrict__ part) {
  float s = 0.f;
  const bool fold = (pb != nullptr);
  for (int i = (blockIdx.x * 256 + threadIdx.x) * 4; i < NELEM; i += 256 * 256 * 4) {
    float4 v = *(const float4*)(x + i);
    if (fold) {
      for (int z = 0; z < np; ++z) {
        float4 a = *(const float4*)(pb + (size_t)z * NELEM + i);
        v.x += a.x; v.y += a.y; v.z += a.z; v.w += a.w;
      }
      float4 c = *(const float4*)(bias + (i & (EDIM - 1)));
      v.x += c.x; v.y += c.y; v.z += c.z; v.w += c.w;
      *(float4*)(x + i) = v;
    }
    s += v.x * v.x + v.y * v.y + v.z * v.z + v.w * v.w;
  }
#pragma unroll
  for (int o = 32; o > 0; o >>= 1) s += __shfl_down(s, o);
  __shared__ float sm[4];
  if ((threadIdx.x & 63) == 0) sm[threadIdx.x >> 6] = s;
  __syncthreads();
  if (threadIdx.x == 0) part[blockIdx.x] = sm[0] + sm[1] + sm[2] + sm[3];
}

// ------------------------------------------------- weight convert + transpose
// src [K][N] f32 -> dst [Npad][Kpad] bf16, optionally row-scaled by gk[k]
__device__ __forceinline__ void conv_tile(const float* __restrict__ src,
                                          const float* __restrict__ gk,
                                          __bf16* __restrict__ dst,
                                          int K, int N, int Kpad, int tk, int tn) {
  __shared__ float st[64][65];
  const int k0 = tk << 6, n0 = tn << 6;
  const int tid = threadIdx.x;
  {
    const int r0 = tid >> 4, c4 = (tid & 15) << 2;
#pragma unroll
    for (int i = 0; i < 4; ++i) {
      const int r = r0 + i * 16;
      const int k = k0 + r;
      float4 v = make_float4(0.f, 0.f, 0.f, 0.f);
      if (k < K) {
        const float* sp = src + (size_t)k * N + n0 + c4;
        if (n0 + c4 + 3 < N) v = *(const float4*)sp;
        else {
          if (n0 + c4 + 0 < N) v.x = sp[0];
          if (n0 + c4 + 1 < N) v.y = sp[1];
          if (n0 + c4 + 2 < N) v.z = sp[2];
          if (n0 + c4 + 3 < N) v.w = sp[3];
        }
        if (gk) {
          const float gv = gk[k];
          v.x *= gv; v.y *= gv; v.z *= gv; v.w *= gv;
        }
      }
      st[r][c4 + 0] = v.x; st[r][c4 + 1] = v.y; st[r][c4 + 2] = v.z; st[r][c4 + 3] = v.w;
    }
  }
  __syncthreads();
  {
    const int nl0 = tid >> 3, c8 = (tid & 7) << 3;
#pragma unroll
    for (int i = 0; i < 2; ++i) {
      const int nl = nl0 + i * 32;
      bf16x8 o = {(__bf16)st[c8 + 0][nl], (__bf16)st[c8 + 1][nl],
                  (__bf16)st[c8 + 2][nl], (__bf16)st[c8 + 3][nl],
                  (__bf16)st[c8 + 4][nl], (__bf16)st[c8 + 5][nl],
                  (__bf16)st[c8 + 6][nl], (__bf16)st[c8 + 7][nl]};
      *(bf16x8*)&dst[(size_t)(n0 + nl) * Kpad + k0 + c8] = o;
    }
  }
}

__global__ __launch_bounds__(256) void k_convAll(const float* __restrict__ Wqkv,
                                                 const float* __restrict__ Wo,
                                                 const float* __restrict__ W1,
                                                 const float* __restrict__ W3,
                                                 const float* __restrict__ W2w,
                                                 const float* __restrict__ g_mha,
                                                 const float* __restrict__ g_ff,
                                                 __bf16* qkvT, __bf16* woT,
                                                 __bf16* w1T, __bf16* w3T, __bf16* w2T) {
  int b = blockIdx.x;
  const int l = b / 3088; b -= l * 3088;
  if (b < 768) {
    conv_tile(Wqkv + (size_t)l * 1024 * 3072, g_mha + (size_t)l * EDIM,
              qkvT + (size_t)l * 3072 * 1024, 1024, 3072, 1024, b / 48, b % 48);
  } else if (b < 1024) {
    int t = b - 768;
    conv_tile(Wo + (size_t)l * 1024 * 1024, nullptr,
              woT + (size_t)l * 1024 * 1024, 1024, 1024, 1024, t / 16, t % 16);
  } else if (b < 1712) {
    int t = b - 1024;
    conv_tile(W1 + (size_t)l * 1024 * DFFDIM, g_ff + (size_t)l * EDIM,
              w1T + (size_t)l * DPAD * 1024, 1024, DFFDIM, 1024, t / 43, t % 43);
  } else if (b < 2400) {
    int t = b - 1712;
    conv_tile(W3 + (size_t)l * 1024 * DFFDIM, g_ff + (size_t)l * EDIM,
              w3T + (size_t)l * DPAD * 1024, 1024, DFFDIM, 1024, t / 43, t % 43);
  } else {
    int t = b - 2400;
    conv_tile(W2w + (size_t)l * DFFDIM * 1024, nullptr,
              w2T + (size_t)l * 1024 * DPAD, DFFDIM, 1024, DPAD, t / 16, t % 16);
  }
}

__global__ __launch_bounds__(256) void k_convH(const float* __restrict__ Wout,
                                               const float* __restrict__ g_final,
                                               __bf16* __restrict__ WoutT) {
  conv_tile(Wout, g_final, WoutT, 1024, VOCAB, 1024, blockIdx.x >> 7, blockIdx.x & 127);
}

// ================================================================ MFMA GEMM
// BM=128, BN in {64,128}; BK=64; 4 waves, wave tile 64 x BN/2.
// FUSE=1: A from f32 x (reg-staged cvt->ds_write, XOR-swizzled), RMS scalar in epilogue.
// FUSE=0: A bf16 via global_load_lds, counted vmcnt.
// MODE: 0=qkv scatter  1=split-K partial (f32)  2=SwiGLU dual  3=head
template <int BN, int MODE, int FUSE>
__global__ __launch_bounds__(256) void mm(
    const __bf16* __restrict__ A, const float* __restrict__ Af,
    const __bf16* __restrict__ B0w, const __bf16* __restrict__ B1w,
    const float* __restrict__ bias0, const float* __restrict__ bias1,
    const float* __restrict__ part,
    float* __restrict__ po, __bf16* __restrict__ ob,
    __bf16* __restrict__ qout, __bf16* __restrict__ kout, __bf16* __restrict__ vout,
    int N, int lda, int ldb, int Ktot) {
  constexpr int DUAL = (MODE == 2) ? 2 : 1;
  constexpr int FN = BN / 32;
  constexpr int BL = (BN == 128) ? 4 : 2 * DUAL;
  __shared__ __bf16 As[2][8][128][8];
  __shared__ __bf16 Bs[2][DUAL][8][BN][8];
  const int tid = threadIdx.x, lane = tid & 63, wave = tid >> 6;
  const int m0 = blockIdx.y << 7, n0 = blockIdx.x * BN;
  const int wm0 = (wave >> 1) * 64, wn0 = (wave & 1) * (BN / 2);
  const int lr = lane & 15, kh = lane >> 4;

  const int ktiles = Ktot >> 6;
  const int nt0 = (ktiles + gridDim.z - 1) / gridDim.z;
  const int tbeg = blockIdx.z * nt0;
  const int tend = (ktiles < tbeg + nt0) ? ktiles : (tbeg + nt0);
  const int nt = tend - tbeg;

  f32x4 acc[DUAL][4][FN];
#pragma unroll
  for (int d = 0; d < DUAL; ++d)
#pragma unroll
    for (int mi = 0; mi < 4; ++mi)
#pragma unroll
      for (int fn = 0; fn < FN; ++fn) acc[d][mi][fn] = (f32x4){0.f, 0.f, 0.f, 0.f};

  float4 ar[4][2];
  auto LOADA = [&](int t) {
    const int k0 = (tbeg + t) << 6;
#pragma unroll
    for (int i = 0; i < 4; ++i) {
      const int d = i * 256 + tid;
      const int row = d >> 3, kb = d & 7;
      const float* ap = Af + (size_t)(m0 + row) * lda + k0 + kb * 8;
      ar[i][0] = *(const float4*)ap; ar[i][1] = *(const float4*)(ap + 4);
    }
  };
  auto DSWA = [&](int buf) {
#pragma unroll
    for (int i = 0; i < 4; ++i) {
      const int d = i * 256 + tid;
      const int row = d >> 3, kb = d & 7;
      float4 a = ar[i][0], b = ar[i][1];
      bf16x8 w = {(__bf16)a.x, (__bf16)a.y, (__bf16)a.z, (__bf16)a.w,
                  (__bf16)b.x, (__bf16)b.y, (__bf16)b.z, (__bf16)b.w};
      *(bf16x8*)&As[buf][kb][row ^ kb][0] = w;
    }
  };
  auto STAGEA_G = [&](int buf, int t) {
    const int k0 = (tbeg + t) << 6;
#pragma unroll
    for (int i = 0; i < 4; ++i) {
      const int d = i * 256 + tid;
      gl_lds16(A + (size_t)(m0 + (d & 127)) * lda + k0 + (d >> 7) * 8,
               &As[buf][d >> 7][d & 127][0]);
    }
  };
  auto STAGEB = [&](int buf, int t) {
    const int k0 = (tbeg + t) << 6;
    if (BN == 128) {
#pragma unroll
      for (int i = 0; i < 4; ++i) {
        const int d = i * 256 + tid;
        gl_lds16(B0w + (size_t)(n0 + (d & 127)) * ldb + k0 + (d >> 7) * 8,
                 &Bs[buf][0][d >> 7][d & 127][0]);
      }
    } else {
#pragma unroll
      for (int i = 0; i < 2; ++i) {
        const int d = i * 256 + tid;
        gl_lds16(B0w + (size_t)(n0 + (d & 63)) * ldb + k0 + (d >> 6) * 8,
                 &Bs[buf][0][d >> 6][d & 63][0]);
      }
      if (DUAL == 2) {
#pragma unroll
        for (int i = 0; i < 2; ++i) {
          const int d = i * 256 + tid;
          gl_lds16(B1w + (size_t)(n0 + (d & 63)) * ldb + k0 + (d >> 6) * 8,
                   &Bs[buf][DUAL - 1][d >> 6][d & 63][0]);
        }
      }
    }
  };
  auto COMP = [&](int buf) {
#pragma unroll
    for (int ks = 0; ks < 2; ++ks) {
      const int kidx = ks * 4 + kh;
      bf16x8 af[4];
#pragma unroll
      for (int mi = 0; mi < 4; ++mi) {
        const int r = wm0 + mi * 16 + lr;
        af[mi] = *(const bf16x8*)&As[buf][kidx][FUSE ? (r ^ kidx) : r][0];
      }
#pragma unroll
      for (int d = 0; d < DUAL; ++d)
#pragma unroll
        for (int fn = 0; fn < FN; ++fn) {
          bf16x8 bfr = *(const bf16x8*)&Bs[buf][d][kidx][wn0 + fn * 16 + lr][0];
#pragma unroll
          for (int mi = 0; mi < 4; ++mi)
            acc[d][mi][fn] = MFMA(af[mi], bfr, acc[d][mi][fn]);
        }
    }
  };

  int cur = 0;
  if (FUSE) {
    LOADA(0); STAGEB(0, 0); DSWA(0);
    asm volatile("s_waitcnt lgkmcnt(0)" ::: "memory");
    vmwait<0>(); __builtin_amdgcn_s_barrier();
    for (int t = 0; t < nt - 1; ++t) {
      LOADA(t + 1);
      STAGEB(cur ^ 1, t + 1);
      COMP(cur);
      DSWA(cur ^ 1);
      asm volatile("s_waitcnt lgkmcnt(0)" ::: "memory");
      vmwait<0>(); __builtin_amdgcn_s_barrier();
      cur ^= 1;
    }
    COMP(cur);
  } else {
    STAGEA_G(0, 0); STAGEB(0, 0);
    for (int t = 0; t < nt - 1; ++t) {
      STAGEA_G(cur ^ 1, t + 1); STAGEB(cur ^ 1, t + 1);
      vmwait<4 + BL>();
      __builtin_amdgcn_s_barrier();
      COMP(cur);
      __builtin_amdgcn_s_barrier();
      cur ^= 1;
    }
    vmwait<0>(); __builtin_amdgcn_s_barrier();
    COMP(cur);
  }

  float sc = 1.0f;
  if (FUSE) {
    __shared__ float smr[4];
    float s = part[tid];
#pragma unroll
    for (int o = 32; o > 0; o >>= 1) s += __shfl_down(s, o);
    if ((tid & 63) == 0) smr[tid >> 6] = s;
    __syncthreads();
    sc = 1.0f / sqrtf((smr[0] + smr[1] + smr[2] + smr[3]) / (float)NELEM + EPSF);
  }

#pragma unroll
  for (int mi = 0; mi < 4; ++mi)
#pragma unroll
    for (int fn = 0; fn < FN; ++fn) {
      const int col = n0 + wn0 + fn * 16 + lr;
      if (MODE == 0) {
        const float bs = bias0[col];
        const int h = col / (3 * HDIM);
        const int rsel = (col >> 6) % 3;
        const int s2 = col & (HDIM - 1);
#pragma unroll
        for (int j = 0; j < 4; ++j) {
          const int row = m0 + wm0 + mi * 16 + (kh << 2) + j;
          const int b = row >> 9, t = row & (TSEQ - 1);
          const float v = acc[0][mi][fn][j] * sc + bs;
          if (rsel == 0)      qout[((size_t)(b * NHEAD + h) * TSEQ + t) * HDIM + s2] = (__bf16)v;
          else if (rsel == 1) kout[((size_t)(b * NHEAD + h) * TSEQ + t) * HDIM + s2] = (__bf16)v;
          else                vout[((size_t)(b * NHEAD + h) * HDIM + s2) * TSEQ + t] = (__bf16)v;
        }
      } else if (MODE == 1) {
        float* pz = po + (size_t)blockIdx.z * NELEM;
#pragma unroll
        for (int j = 0; j < 4; ++j) {
          const int row = m0 + wm0 + mi * 16 + (kh << 2) + j;
          pz[(size_t)row * EDIM + col] = acc[0][mi][fn][j];
        }
      } else if (MODE == 2) {
        const bool ok = col < N;
        const float bb1 = ok ? bias0[col] : 0.f;
        const float bb3 = ok ? bias1[col] : 0.f;
#pragma unroll
        for (int j = 0; j < 4; ++j) {
          const int row = m0 + wm0 + mi * 16 + (kh << 2) + j;
          float v = 0.f;
          if (ok) {
            const float a1v = acc[0][mi][fn][j] * sc + bb1;
            const float a3v = acc[DUAL - 1][mi][fn][j] * sc + bb3;
            v = a1v * (1.0f / (1.0f + __expf(-a1v))) * a3v;
          }
          ob[(size_t)row * DPAD + col] = (__bf16)v;
        }
      } else {
        if (col < N) {
          const float bs = bias0[col];
#pragma unroll
          for (int j = 0; j < 4; ++j) {
            const int row = m0 + wm0 + mi * 16 + (kh << 2) + j;
            po[(size_t)row * N + col] = acc[0][mi][fn][j] * sc + bs;
          }
        }
      }
    }
}

// ------------------------------------------------- flash attention (bf16 in)
// 32-row Q tiles -> 512 blocks (2/CU). 4 waves: wave tile 16(m) x 32(n).
// Double-buffered K/V, counted vmcnt; defer-max (T13, THR=8).
__global__ __launch_bounds__(256) void k_flash(const __bf16* __restrict__ qbuf,
                                               const __bf16* __restrict__ kbuf,
                                               const __bf16* __restrict__ vbufT,
                                               __bf16* __restrict__ y2) {
  const int qt = blockIdx.x, bh = blockIdx.y;
  const int b = bh >> 4, h = bh & 15;
  const int m0 = qt << 5;                      // 32-row Q tile
  const __bf16* qp = qbuf  + (size_t)bh * TSEQ * HDIM;
  const __bf16* kp = kbuf  + (size_t)bh * TSEQ * HDIM;
  const __bf16* vp = vbufT + (size_t)bh * HDIM * TSEQ;   // [s][t]
  __shared__ __bf16 Qs[8][32][8], Ks[2][8][64][8], Vs[2][8][64][8], Ps[8][32][8];
  __shared__ float wmax[2][32], wsum[2][32];
  const int tid = threadIdx.x, lane = tid & 63, wave = tid >> 6;
  const int wm = (wave >> 1) << 4, wn = (wave & 1) << 5;
  const int lr = lane & 15, kh = lane >> 4;

  auto STAGE_KV = [&](int kt2, int buf) {      // 4 gl_lds per thread
    const int n0s = kt2 << 6;
#pragma unroll
    for (int i = 0; i < 2; ++i) {
      const int d = i * 256 + tid;
      const int kb2 = d >> 6, row = d & 63;
      gl_lds16(kp + (size_t)(n0s + row) * HDIM + kb2 * 8, &Ks[buf][kb2][row][0]);
      gl_lds16(vp + (size_t)row * TSEQ + n0s + kb2 * 8, &Vs[buf][kb2][row][0]);
    }
  };

  // Q: one 16B deposit per thread (32 rows x 128B)
  gl_lds16(qp + (size_t)(m0 + (tid & 31)) * HDIM + (tid >> 5) * 8,
           &Qs[tid >> 5][tid & 31][0]);
  STAGE_KV(0, 0);

  float m_[4], l_[4];
#pragma unroll
  for (int j = 0; j < 4; ++j) { m_[j] = NEGBIG; l_[j] = 0.f; }
  f32x4 o0 = {0, 0, 0, 0}, o1 = {0, 0, 0, 0};

  const int ktmax = qt >> 1;
  int cur = 0;
  for (int kt = 0; kt <= ktmax; ++kt) {
    const int n0 = kt << 6;
    if (kt < ktmax) {
      STAGE_KV(kt + 1, cur ^ 1);   // next tile stays in flight
      vmwait<4>();                 // Q + tile-kt retired
    } else {
      vmwait<0>();
    }
    __builtin_amdgcn_s_barrier();

    // QK^T: 16x64 per wave
    f32x4 s0 = {0, 0, 0, 0}, s1 = {0, 0, 0, 0};
#pragma unroll
    for (int ks = 0; ks < 2; ++ks) {
      const int kidx = ks * 4 + kh;
      bf16x8 a  = *(const bf16x8*)&Qs[kidx][wm + lr][0];
      bf16x8 b0 = *(const bf16x8*)&Ks[cur][kidx][wn + lr][0];
      bf16x8 b1 = *(const bf16x8*)&Ks[cur][kidx][wn + 16 + lr][0];
      s0 = MFMA(a, b0, s0); s1 = MFMA(a, b1, s1);
    }
    float pv0[4], pv1[4];
#pragma unroll
    for (int j = 0; j < 4; ++j) {
      const int grow = m0 + wm + (kh << 2) + j;
      float t0 = s0[j] * SCALEF; if (n0 + wn + lr > grow)      t0 = NEGBIG;
      float t1 = s1[j] * SCALEF; if (n0 + wn + 16 + lr > grow) t1 = NEGBIG;
      pv0[j] = t0; pv1[j] = t1;
      float v = fmaxf(t0, t1);
      v = fmaxf(v, __shfl_xor(v, 1)); v = fmaxf(v, __shfl_xor(v, 2));
      v = fmaxf(v, __shfl_xor(v, 4)); v = fmaxf(v, __shfl_xor(v, 8));
      wmax[wave & 1][wm + (kh << 2) + j] = v;
    }
    lgkm_barrier();  // wmax visible (vmcnt NOT drained)

    // defer-max: only rescale when a row's max grew past THR=8
    float tmax[4]; bool need = false;
#pragma unroll
    for (int j = 0; j < 4; ++j) {
      const int rl = wm + (kh << 2) + j;
      tmax[j] = fmaxf(wmax[0][rl], wmax[1][rl]);
      need |= (tmax[j] > m_[j] + 8.f);
    }
    if (__ballot(need)) {
#pragma unroll
      for (int j = 0; j < 4; ++j) {
        const float mn = fmaxf(m_[j], tmax[j]);
        const float al = __expf(m_[j] - mn);
        m_[j] = mn; l_[j] *= al; o0[j] *= al; o1[j] *= al;
      }
    }
#pragma unroll
    for (int j = 0; j < 4; ++j) {
      const float p0 = __expf(pv0[j] - m_[j]);
      const float p1 = __expf(pv1[j] - m_[j]);
      float rs = p0 + p1;
      rs += __shfl_xor(rs, 1); rs += __shfl_xor(rs, 2);
      rs += __shfl_xor(rs, 4); rs += __shfl_xor(rs, 8);
      const int rl = wm + (kh << 2) + j;
      wsum[wave & 1][rl] = rs;
      const int pc0 = wn + lr, pc1 = wn + 16 + lr;
      Ps[pc0 >> 3][rl][pc0 & 7] = (__bf16)p0;
      Ps[pc1 >> 3][rl][pc1 & 7] = (__bf16)p1;
    }
    lgkm_barrier();  // wsum & Ps visible

#pragma unroll
    for (int j = 0; j < 4; ++j) {
      const int rl = wm + (kh << 2) + j;
      l_[j] += wsum[0][rl] + wsum[1][rl];
    }
    // PV: 16x64 per wave
#pragma unroll
    for (int ks = 0; ks < 2; ++ks) {
      const int kidx = ks * 4 + kh;
      bf16x8 a  = *(const bf16x8*)&Ps[kidx][wm + lr][0];
      bf16x8 b0 = *(const bf16x8*)&Vs[cur][kidx][wn + lr][0];
      bf16x8 b1 = *(const bf16x8*)&Vs[cur][kidx][wn + 16 + lr][0];
      o0 = MFMA(a, b0, o0); o1 = MFMA(a, b1, o1);
    }
    __builtin_amdgcn_s_barrier();  // readers done before buffer overwrite
    cur ^= 1;
  }

#pragma unroll
  for (int j = 0; j < 4; ++j) {
    const int row = m0 + wm + (kh << 2) + j;
    const float inv = 1.0f / l_[j];
    y2[((size_t)(b * TSEQ) + row) * EDIM + h * HDIM + wn + lr]      = (__bf16)(o0[j] * inv);
    y2[((size_t)(b * TSEQ) + row) * EDIM + h * HDIM + wn + 16 + lr] = (__bf16)(o1[j] * inv);
  }
}

// ---------------------------------------------------------------- launcher
extern "C" void kernel_launch(void* const* d_in, const int* in_sizes, int n_in,
                              void* d_out, int out_size, void* d_ws, size_t ws_size,
                              hipStream_t stream) {
  const int*   tokens  = (const int*)d_in[0];
  const float* emb     = (const float*)d_in[1];
  const float* Wqkv    = (const float*)d_in[2];
  const float* bqkv    = (const float*)d_in[3];
  const float* Wo      = (const float*)d_in[4];
  const float* bo      = (const float*)d_in[5];
  const float* W1      = (const float*)d_in[6];
  const float* b1      = (const float*)d_in[7];
  const float* W3      = (const float*)d_in[8];
  const float* b3      = (const float*)d_in[9];
  const float* W2w     = (const float*)d_in[10];
  const float* b2      = (const float*)d_in[11];
  const float* g_mha   = (const float*)d_in[12];
  const float* g_ff    = (const float*)d_in[13];
  const float* g_final = (const float*)d_in[14];
  const float* Wout    = (const float*)d_in[15];
  const float* bout    = (const float*)d_in[16];
  float* out = (float*)d_out;

  char* base = (char*)d_ws;
  size_t off = 0;
  auto alloc = [&](size_t bytes) { char* p = base + off; off = (off + bytes + 255) & ~(size_t)255; return p; };
  float*  x    = (float*)alloc(4u << 20);
  float*  part = (float*)alloc(2048);
  __bf16* qbf  = (__bf16*)alloc(2u << 20);
  __bf16* kbf  = (__bf16*)alloc(2u << 20);
  __bf16* vbT  = (__bf16*)alloc(2u << 20);
  __bf16* y2bf = (__bf16*)alloc(2u << 20);
  __bf16* ubf  = (__bf16*)alloc((size_t)MTOK * DPAD * 2);
  float*  pbuf = (float*)alloc((size_t)4 * NELEM * 4);
  __bf16* WoutT = (__bf16*)alloc((size_t)8192 * 1024 * 2);
  __bf16* qkvT = (__bf16*)alloc((size_t)NLAYER * 3072 * 1024 * 2);
  __bf16* woT  = (__bf16*)alloc((size_t)NLAYER * 1024 * 1024 * 2);
  __bf16* w1T  = (__bf16*)alloc((size_t)NLAYER * DPAD * 1024 * 2);
  __bf16* w3T  = (__bf16*)alloc((size_t)NLAYER * DPAD * 1024 * 2);
  __bf16* w2T  = (__bf16*)alloc((size_t)NLAYER * 1024 * DPAD * 2);

  k_embed<<<MTOK, 256, 0, stream>>>(tokens, emb, x);
  k_convAll<<<NLAYER * 3088, 256, 0, stream>>>(Wqkv, Wo, W1, W3, W2w,
                                               g_mha, g_ff,
                                               qkvT, woT, w1T, w3T, w2T);
  k_convH<<<2048, 256, 0, stream>>>(Wout, g_final, WoutT);

  const float* pend_bias = nullptr;
  for (int l = 0; l < NLAYER; ++l) {
    // --- MHA ---
    k_red1f<<<256, 256, 0, stream>>>(x, pend_bias ? pbuf : nullptr, 4, pend_bias, part);
    mm<64, 0, 1><<<dim3(48, 8, 1), 256, 0, stream>>>(
        nullptr, x, qkvT + (size_t)l * 3072 * 1024, nullptr,
        bqkv + (size_t)l * 3 * EDIM, nullptr, part,
        nullptr, nullptr, qbf, kbf, vbT, 3072, EDIM, 1024, 1024);
    k_flash<<<dim3(16, 32), 256, 0, stream>>>(qbf, kbf, vbT, y2bf);
    mm<64, 1, 0><<<dim3(16, 8, 4), 256, 0, stream>>>(
        y2bf, nullptr, woT + (size_t)l * 1024 * 1024, nullptr,
        nullptr, nullptr, nullptr,
        pbuf, nullptr, nullptr, nullptr, nullptr, 1024, 1024, 1024, 1024);
    // --- SwiGLU FFN ---
    k_red1f<<<256, 256, 0, stream>>>(x, pbuf, 4, bo + (size_t)l * EDIM, part);
    mm<64, 2, 1><<<dim3(43, 8, 1), 256, 0, stream>>>(
        nullptr, x, w1T + (size_t)l * DPAD * 1024, w3T + (size_t)l * DPAD * 1024,
        b1 + (size_t)l * DFFDIM, b3 + (size_t)l * DFFDIM, part,
        nullptr, ubf, nullptr, nullptr, nullptr, DFFDIM, EDIM, 1024, 1024);
    mm<64, 1, 0><<<dim3(16, 8, 4), 256, 0, stream>>>(
        ubf, nullptr, w2T + (size_t)l * 1024 * DPAD, nullptr,
        nullptr, nullptr, nullptr,
        pbuf, nullptr, nullptr, nullptr, nullptr, 1024, DPAD, DPAD, DPAD);
    pend_bias = b2 + (size_t)l * EDIM;
  }

  // --- final RMS + vocab head ---
  k_red1f<<<256, 256, 0, stream>>>(x, pbuf, 4, pend_bias, part);
  mm<128, 3, 1><<<dim3(64, 8, 1), 256, 0, stream>>>(
      nullptr, x, WoutT, nullptr, bout, nullptr, part,
      out, nullptr, nullptr, nullptr, nullptr, VOCAB, EDIM, 1024, 1024);
}

// Round 10
// 3886.489 us; speedup vs baseline: 1.0858x; 1.0192x over previous
//
#include <hip/hip_runtime.h>
#include <hip/hip_bf16.h>
#include <math.h>

#define EDIM   1024
#define TSEQ   512
#define NBATCH 2
#define NHEAD  16
#define HDIM   64
#define NLAYER 24
#define VOCAB  8124
#define DFFDIM 2730
#define DPAD   2752              // 43*64 padded SwiGLU width
#define MTOK   (NBATCH*TSEQ)     // 1024
#define NELEM  (MTOK*EDIM)
#define EPSF   1e-5f
#define SCALEF (1.0f/32.0f)
#define NEGBIG (-1e30f)

typedef __bf16 bf16x8 __attribute__((ext_vector_type(8)));
typedef __bf16 bf16x4 __attribute__((ext_vector_type(4)));
typedef float  f32x4  __attribute__((ext_vector_type(4)));

#define MFMA(a, b, c) __builtin_amdgcn_mfma_f32_16x16x32_bf16((a), (b), (c), 0, 0, 0)

__device__ __forceinline__ void gl_lds16(const __bf16* g, __bf16* l) {
  __builtin_amdgcn_global_load_lds(
      (const __attribute__((address_space(1))) void*)g,
      (__attribute__((address_space(3))) void*)l, 16, 0, 0);
}
template <int N> __device__ __forceinline__ void vmwait() {
  asm volatile("s_waitcnt vmcnt(%0)" :: "n"(N) : "memory");
}
__device__ __forceinline__ void lgkm_barrier() {
  asm volatile("s_waitcnt lgkmcnt(0)" ::: "memory");
  __builtin_amdgcn_s_barrier();
}

// ---------------------------------------------------------------- embedding+PE
__global__ __launch_bounds__(256) void k_embed(const int* __restrict__ tok,
                                               const float* __restrict__ emb,
                                               float* __restrict__ x) {
  const int bt = blockIdx.x;
  const int t  = bt & (TSEQ - 1);
  const int tk = tok[bt];
  const float* er = emb + (size_t)tk * EDIM;
  float* xr = x + (size_t)bt * EDIM;
  for (int e = threadIdx.x * 4; e < EDIM; e += 256 * 4) {
    float4 v = *(const float4*)(er + e);
    float vv[4] = {v.x, v.y, v.z, v.w};
    float ou[4];
#pragma unroll
    for (int j = 0; j < 4; ++j) {
      int ee = e + j;
      int i2 = ee & ~1;
      float freq = expf(-(float)i2 * (9.210340371976184f / 1024.0f));
      float ang  = (float)t * freq;
      ou[j] = vv[j] + ((ee & 1) ? cosf(ang) : sinf(ang));
    }
    *(float4*)(xr + e) = make_float4(ou[0], ou[1], ou[2], ou[3]);
  }
}

// ----------------- RMS reduce (+fold np partials) + emit bf16(x) for GEMM A
__global__ __launch_bounds__(256) void k_red1f(float* __restrict__ x,
                                               const float* __restrict__ pb,
                                               int np,
                                               const float* __restrict__ bias,
                                               float* __restrict__ part,
                                               __bf16* __restrict__ ybf) {
  float s = 0.f;
  const bool fold = (pb != nullptr);
  for (int i = (blockIdx.x * 256 + threadIdx.x) * 4; i < NELEM; i += 256 * 256 * 4) {
    float4 v = *(const float4*)(x + i);
    if (fold) {
      for (int z = 0; z < np; ++z) {
        float4 a = *(const float4*)(pb + (size_t)z * NELEM + i);
        v.x += a.x; v.y += a.y; v.z += a.z; v.w += a.w;
      }
      float4 c = *(const float4*)(bias + (i & (EDIM - 1)));
      v.x += c.x; v.y += c.y; v.z += c.z; v.w += c.w;
      *(float4*)(x + i) = v;
    }
    bf16x4 o = {(__bf16)v.x, (__bf16)v.y, (__bf16)v.z, (__bf16)v.w};
    *(bf16x4*)(ybf + i) = o;
    s += v.x * v.x + v.y * v.y + v.z * v.z + v.w * v.w;
  }
#pragma unroll
  for (int o = 32; o > 0; o >>= 1) s += __shfl_down(s, o);
  __shared__ float sm[4];
  if ((threadIdx.x & 63) == 0) sm[threadIdx.x >> 6] = s;
  __syncthreads();
  if (threadIdx.x == 0) part[blockIdx.x] = sm[0] + sm[1] + sm[2] + sm[3];
}

// ------------------------------------------------- weight convert + transpose
// src [K][N] f32 -> dst [Npad][Kpad] bf16, row-scaled by gk[k]. Non-temporal
// loads/stores (ext-vector types): weights are read-once/written-once.
__device__ __forceinline__ void conv_tile(const float* __restrict__ src,
                                          const float* __restrict__ gk,
                                          __bf16* __restrict__ dst,
                                          int K, int N, int Kpad, int tk, int tn) {
  __shared__ float st[64][65];
  const int k0 = tk << 6, n0 = tn << 6;
  const int tid = threadIdx.x;
  {
    const int r0 = tid >> 4, c4 = (tid & 15) << 2;
#pragma unroll
    for (int i = 0; i < 4; ++i) {
      const int r = r0 + i * 16;
      const int k = k0 + r;
      f32x4 v = {0.f, 0.f, 0.f, 0.f};
      if (k < K) {
        const float* sp = src + (size_t)k * N + n0 + c4;
        if (n0 + c4 + 3 < N) v = __builtin_nontemporal_load((const f32x4*)sp);
        else {
          if (n0 + c4 + 0 < N) v[0] = sp[0];
          if (n0 + c4 + 1 < N) v[1] = sp[1];
          if (n0 + c4 + 2 < N) v[2] = sp[2];
          if (n0 + c4 + 3 < N) v[3] = sp[3];
        }
        if (gk) {
          const float gv = gk[k];
          v[0] *= gv; v[1] *= gv; v[2] *= gv; v[3] *= gv;
        }
      }
      st[r][c4 + 0] = v[0]; st[r][c4 + 1] = v[1];
      st[r][c4 + 2] = v[2]; st[r][c4 + 3] = v[3];
    }
  }
  __syncthreads();
  {
    const int nl0 = tid >> 3, c8 = (tid & 7) << 3;
#pragma unroll
    for (int i = 0; i < 2; ++i) {
      const int nl = nl0 + i * 32;
      bf16x8 o = {(__bf16)st[c8 + 0][nl], (__bf16)st[c8 + 1][nl],
                  (__bf16)st[c8 + 2][nl], (__bf16)st[c8 + 3][nl],
                  (__bf16)st[c8 + 4][nl], (__bf16)st[c8 + 5][nl],
                  (__bf16)st[c8 + 6][nl], (__bf16)st[c8 + 7][nl]};
      __builtin_nontemporal_store(o, (bf16x8*)&dst[(size_t)(n0 + nl) * Kpad + k0 + c8]);
    }
  }
}

__global__ __launch_bounds__(256) void k_convAll(const float* __restrict__ Wqkv,
                                                 const float* __restrict__ Wo,
                                                 const float* __restrict__ W1,
                                                 const float* __restrict__ W3,
                                                 const float* __restrict__ W2w,
                                                 const float* __restrict__ g_mha,
                                                 const float* __restrict__ g_ff,
                                                 __bf16* qkvT, __bf16* woT,
                                                 __bf16* w1T, __bf16* w3T, __bf16* w2T) {
  int b = blockIdx.x;
  const int l = b / 3088; b -= l * 3088;
  if (b < 768) {
    conv_tile(Wqkv + (size_t)l * 1024 * 3072, g_mha + (size_t)l * EDIM,
              qkvT + (size_t)l * 3072 * 1024, 1024, 3072, 1024, b / 48, b % 48);
  } else if (b < 1024) {
    int t = b - 768;
    conv_tile(Wo + (size_t)l * 1024 * 1024, nullptr,
              woT + (size_t)l * 1024 * 1024, 1024, 1024, 1024, t / 16, t % 16);
  } else if (b < 1712) {
    int t = b - 1024;
    conv_tile(W1 + (size_t)l * 1024 * DFFDIM, g_ff + (size_t)l * EDIM,
              w1T + (size_t)l * DPAD * 1024, 1024, DFFDIM, 1024, t / 43, t % 43);
  } else if (b < 2400) {
    int t = b - 1712;
    conv_tile(W3 + (size_t)l * 1024 * DFFDIM, g_ff + (size_t)l * EDIM,
              w3T + (size_t)l * DPAD * 1024, 1024, DFFDIM, 1024, t / 43, t % 43);
  } else {
    int t = b - 2400;
    conv_tile(W2w + (size_t)l * DFFDIM * 1024, nullptr,
              w2T + (size_t)l * 1024 * DPAD, DFFDIM, 1024, DPAD, t / 16, t % 16);
  }
}

__global__ __launch_bounds__(256) void k_convH(const float* __restrict__ Wout,
                                               const float* __restrict__ g_final,
                                               __bf16* __restrict__ WoutT) {
  conv_tile(Wout, g_final, WoutT, 1024, VOCAB, 1024, blockIdx.x >> 7, blockIdx.x & 127);
}

// ================================================================ MFMA GEMM
// BM=128, BN in {64,128}; BK=64; 4 waves, wave tile 64 x BN/2.
// A bf16 via global_load_lds (from ybf = bf16(x) emitted by red1f), counted
// vmcnt double-buffer. SC=1: epilogue multiplies acc by the RMS scalar
// (re-reduced from part[256]; weights are pre-scaled by g at conversion).
// MODE: 0=qkv scatter  1=split-K partial (f32)  2=SwiGLU dual  3=head
template <int BN, int MODE, int SC>
__global__ __launch_bounds__(256) void mm(
    const __bf16* __restrict__ A,
    const __bf16* __restrict__ B0w, const __bf16* __restrict__ B1w,
    const float* __restrict__ bias0, const float* __restrict__ bias1,
    const float* __restrict__ part,
    float* __restrict__ po, __bf16* __restrict__ ob,
    __bf16* __restrict__ qout, __bf16* __restrict__ kout, __bf16* __restrict__ vout,
    int N, int lda, int ldb, int Ktot) {
  constexpr int DUAL = (MODE == 2) ? 2 : 1;
  constexpr int FN = BN / 32;
  constexpr int BL = (BN == 128) ? 4 : 2 * DUAL;
  __shared__ __bf16 As[2][8][128][8];
  __shared__ __bf16 Bs[2][DUAL][8][BN][8];
  const int tid = threadIdx.x, lane = tid & 63, wave = tid >> 6;
  const int m0 = blockIdx.y << 7, n0 = blockIdx.x * BN;
  const int wm0 = (wave >> 1) * 64, wn0 = (wave & 1) * (BN / 2);
  const int lr = lane & 15, kh = lane >> 4;

  const int ktiles = Ktot >> 6;
  const int nt0 = (ktiles + gridDim.z - 1) / gridDim.z;
  const int tbeg = blockIdx.z * nt0;
  const int tend = (ktiles < tbeg + nt0) ? ktiles : (tbeg + nt0);
  const int nt = tend - tbeg;

  f32x4 acc[DUAL][4][FN];
#pragma unroll
  for (int d = 0; d < DUAL; ++d)
#pragma unroll
    for (int mi = 0; mi < 4; ++mi)
#pragma unroll
      for (int fn = 0; fn < FN; ++fn) acc[d][mi][fn] = (f32x4){0.f, 0.f, 0.f, 0.f};

  auto STAGE = [&](int buf, int t) {
    const int k0 = (tbeg + t) << 6;
#pragma unroll
    for (int i = 0; i < 4; ++i) {
      const int d = i * 256 + tid;
      gl_lds16(A + (size_t)(m0 + (d & 127)) * lda + k0 + (d >> 7) * 8,
               &As[buf][d >> 7][d & 127][0]);
    }
    if (BN == 128) {
#pragma unroll
      for (int i = 0; i < 4; ++i) {
        const int d = i * 256 + tid;
        gl_lds16(B0w + (size_t)(n0 + (d & 127)) * ldb + k0 + (d >> 7) * 8,
                 &Bs[buf][0][d >> 7][d & 127][0]);
      }
    } else {
#pragma unroll
      for (int i = 0; i < 2; ++i) {
        const int d = i * 256 + tid;
        gl_lds16(B0w + (size_t)(n0 + (d & 63)) * ldb + k0 + (d >> 6) * 8,
                 &Bs[buf][0][d >> 6][d & 63][0]);
      }
      if (DUAL == 2) {
#pragma unroll
        for (int i = 0; i < 2; ++i) {
          const int d = i * 256 + tid;
          gl_lds16(B1w + (size_t)(n0 + (d & 63)) * ldb + k0 + (d >> 6) * 8,
                   &Bs[buf][DUAL - 1][d >> 6][d & 63][0]);
        }
      }
    }
  };
  auto COMP = [&](int buf) {
#pragma unroll
    for (int ks = 0; ks < 2; ++ks) {
      const int kidx = ks * 4 + kh;
      bf16x8 af[4];
#pragma unroll
      for (int mi = 0; mi < 4; ++mi)
        af[mi] = *(const bf16x8*)&As[buf][kidx][wm0 + mi * 16 + lr][0];
#pragma unroll
      for (int d = 0; d < DUAL; ++d)
#pragma unroll
        for (int fn = 0; fn < FN; ++fn) {
          bf16x8 bfr = *(const bf16x8*)&Bs[buf][d][kidx][wn0 + fn * 16 + lr][0];
#pragma unroll
          for (int mi = 0; mi < 4; ++mi)
            acc[d][mi][fn] = MFMA(af[mi], bfr, acc[d][mi][fn]);
        }
    }
  };

  STAGE(0, 0);
  int cur = 0;
  for (int t = 0; t < nt - 1; ++t) {
    STAGE(cur ^ 1, t + 1);          // next tile stays in flight
    vmwait<4 + BL>();               // own tile-t loads retired
    __builtin_amdgcn_s_barrier();
    COMP(cur);
    __builtin_amdgcn_s_barrier();
    cur ^= 1;
  }
  vmwait<0>();
  __builtin_amdgcn_s_barrier();
  COMP(cur);

  float sc = 1.0f;
  if (SC) {
    __shared__ float smr[4];
    float s = part[tid];
#pragma unroll
    for (int o = 32; o > 0; o >>= 1) s += __shfl_down(s, o);
    if ((tid & 63) == 0) smr[tid >> 6] = s;
    __syncthreads();
    sc = 1.0f / sqrtf((smr[0] + smr[1] + smr[2] + smr[3]) / (float)NELEM + EPSF);
  }

#pragma unroll
  for (int mi = 0; mi < 4; ++mi)
#pragma unroll
    for (int fn = 0; fn < FN; ++fn) {
      const int col = n0 + wn0 + fn * 16 + lr;
      if (MODE == 0) {
        const float bs = bias0[col];
        const int h = col / (3 * HDIM);
        const int rsel = (col >> 6) % 3;
        const int s2 = col & (HDIM - 1);
#pragma unroll
        for (int j = 0; j < 4; ++j) {
          const int row = m0 + wm0 + mi * 16 + (kh << 2) + j;
          const int b = row >> 9, t = row & (TSEQ - 1);
          const float v = acc[0][mi][fn][j] * sc + bs;
          if (rsel == 0)      qout[((size_t)(b * NHEAD + h) * TSEQ + t) * HDIM + s2] = (__bf16)v;
          else if (rsel == 1) kout[((size_t)(b * NHEAD + h) * TSEQ + t) * HDIM + s2] = (__bf16)v;
          else                vout[((size_t)(b * NHEAD + h) * HDIM + s2) * TSEQ + t] = (__bf16)v;
        }
      } else if (MODE == 1) {
        float* pz = po + (size_t)blockIdx.z * NELEM;
#pragma unroll
        for (int j = 0; j < 4; ++j) {
          const int row = m0 + wm0 + mi * 16 + (kh << 2) + j;
          pz[(size_t)row * EDIM + col] = acc[0][mi][fn][j];
        }
      } else if (MODE == 2) {
        const bool ok = col < N;
        const float bb1 = ok ? bias0[col] : 0.f;
        const float bb3 = ok ? bias1[col] : 0.f;
#pragma unroll
        for (int j = 0; j < 4; ++j) {
          const int row = m0 + wm0 + mi * 16 + (kh << 2) + j;
          float v = 0.f;
          if (ok) {
            const float a1v = acc[0][mi][fn][j] * sc + bb1;
            const float a3v = acc[DUAL - 1][mi][fn][j] * sc + bb3;
            v = a1v * (1.0f / (1.0f + __expf(-a1v))) * a3v;
          }
          ob[(size_t)row * DPAD + col] = (__bf16)v;
        }
      } else {
        if (col < N) {
          const float bs = bias0[col];
#pragma unroll
          for (int j = 0; j < 4; ++j) {
            const int row = m0 + wm0 + mi * 16 + (kh << 2) + j;
            po[(size_t)row * N + col] = acc[0][mi][fn][j] * sc + bs;
          }
        }
      }
    }
}

// ------------------------------------------------- flash attention (bf16 in)
// 32-row Q tiles -> 512 blocks (2/CU). 4 waves: wave tile 16(m) x 32(n).
// Double-buffered K/V, counted vmcnt; defer-max (T13, THR=8).
__global__ __launch_bounds__(256) void k_flash(const __bf16* __restrict__ qbuf,
                                               const __bf16* __restrict__ kbuf,
                                               const __bf16* __restrict__ vbufT,
                                               __bf16* __restrict__ y2) {
  const int qt = blockIdx.x, bh = blockIdx.y;
  const int b = bh >> 4, h = bh & 15;
  const int m0 = qt << 5;                      // 32-row Q tile
  const __bf16* qp = qbuf  + (size_t)bh * TSEQ * HDIM;
  const __bf16* kp = kbuf  + (size_t)bh * TSEQ * HDIM;
  const __bf16* vp = vbufT + (size_t)bh * HDIM * TSEQ;   // [s][t]
  __shared__ __bf16 Qs[8][32][8], Ks[2][8][64][8], Vs[2][8][64][8], Ps[8][32][8];
  __shared__ float wmax[2][32], wsum[2][32];
  const int tid = threadIdx.x, lane = tid & 63, wave = tid >> 6;
  const int wm = (wave >> 1) << 4, wn = (wave & 1) << 5;
  const int lr = lane & 15, kh = lane >> 4;

  auto STAGE_KV = [&](int kt2, int buf) {      // 4 gl_lds per thread
    const int n0s = kt2 << 6;
#pragma unroll
    for (int i = 0; i < 2; ++i) {
      const int d = i * 256 + tid;
      const int kb2 = d >> 6, row = d & 63;
      gl_lds16(kp + (size_t)(n0s + row) * HDIM + kb2 * 8, &Ks[buf][kb2][row][0]);
      gl_lds16(vp + (size_t)row * TSEQ + n0s + kb2 * 8, &Vs[buf][kb2][row][0]);
    }
  };

  gl_lds16(qp + (size_t)(m0 + (tid & 31)) * HDIM + (tid >> 5) * 8,
           &Qs[tid >> 5][tid & 31][0]);
  STAGE_KV(0, 0);

  float m_[4], l_[4];
#pragma unroll
  for (int j = 0; j < 4; ++j) { m_[j] = NEGBIG; l_[j] = 0.f; }
  f32x4 o0 = {0, 0, 0, 0}, o1 = {0, 0, 0, 0};

  const int ktmax = qt >> 1;
  int cur = 0;
  for (int kt = 0; kt <= ktmax; ++kt) {
    const int n0 = kt << 6;
    if (kt < ktmax) {
      STAGE_KV(kt + 1, cur ^ 1);
      vmwait<4>();
    } else {
      vmwait<0>();
    }
    __builtin_amdgcn_s_barrier();

    f32x4 s0 = {0, 0, 0, 0}, s1 = {0, 0, 0, 0};
#pragma unroll
    for (int ks = 0; ks < 2; ++ks) {
      const int kidx = ks * 4 + kh;
      bf16x8 a  = *(const bf16x8*)&Qs[kidx][wm + lr][0];
      bf16x8 b0 = *(const bf16x8*)&Ks[cur][kidx][wn + lr][0];
      bf16x8 b1 = *(const bf16x8*)&Ks[cur][kidx][wn + 16 + lr][0];
      s0 = MFMA(a, b0, s0); s1 = MFMA(a, b1, s1);
    }
    float pv0[4], pv1[4];
#pragma unroll
    for (int j = 0; j < 4; ++j) {
      const int grow = m0 + wm + (kh << 2) + j;
      float t0 = s0[j] * SCALEF; if (n0 + wn + lr > grow)      t0 = NEGBIG;
      float t1 = s1[j] * SCALEF; if (n0 + wn + 16 + lr > grow) t1 = NEGBIG;
      pv0[j] = t0; pv1[j] = t1;
      float v = fmaxf(t0, t1);
      v = fmaxf(v, __shfl_xor(v, 1)); v = fmaxf(v, __shfl_xor(v, 2));
      v = fmaxf(v, __shfl_xor(v, 4)); v = fmaxf(v, __shfl_xor(v, 8));
      wmax[wave & 1][wm + (kh << 2) + j] = v;
    }
    lgkm_barrier();

    float tmax[4]; bool need = false;
#pragma unroll
    for (int j = 0; j < 4; ++j) {
      const int rl = wm + (kh << 2) + j;
      tmax[j] = fmaxf(wmax[0][rl], wmax[1][rl]);
      need |= (tmax[j] > m_[j] + 8.f);
    }
    if (__ballot(need)) {
#pragma unroll
      for (int j = 0; j < 4; ++j) {
        const float mn = fmaxf(m_[j], tmax[j]);
        const float al = __expf(m_[j] - mn);
        m_[j] = mn; l_[j] *= al; o0[j] *= al; o1[j] *= al;
      }
    }
#pragma unroll
    for (int j = 0; j < 4; ++j) {
      const float p0 = __expf(pv0[j] - m_[j]);
      const float p1 = __expf(pv1[j] - m_[j]);
      float rs = p0 + p1;
      rs += __shfl_xor(rs, 1); rs += __shfl_xor(rs, 2);
      rs += __shfl_xor(rs, 4); rs += __shfl_xor(rs, 8);
      const int rl = wm + (kh << 2) + j;
      wsum[wave & 1][rl] = rs;
      const int pc0 = wn + lr, pc1 = wn + 16 + lr;
      Ps[pc0 >> 3][rl][pc0 & 7] = (__bf16)p0;
      Ps[pc1 >> 3][rl][pc1 & 7] = (__bf16)p1;
    }
    lgkm_barrier();

#pragma unroll
    for (int j = 0; j < 4; ++j) {
      const int rl = wm + (kh << 2) + j;
      l_[j] += wsum[0][rl] + wsum[1][rl];
    }
#pragma unroll
    for (int ks = 0; ks < 2; ++ks) {
      const int kidx = ks * 4 + kh;
      bf16x8 a  = *(const bf16x8*)&Ps[kidx][wm + lr][0];
      bf16x8 b0 = *(const bf16x8*)&Vs[cur][kidx][wn + lr][0];
      bf16x8 b1 = *(const bf16x8*)&Vs[cur][kidx][wn + 16 + lr][0];
      o0 = MFMA(a, b0, o0); o1 = MFMA(a, b1, o1);
    }
    __builtin_amdgcn_s_barrier();
    cur ^= 1;
  }

#pragma unroll
  for (int j = 0; j < 4; ++j) {
    const int row = m0 + wm + (kh << 2) + j;
    const float inv = 1.0f / l_[j];
    y2[((size_t)(b * TSEQ) + row) * EDIM + h * HDIM + wn + lr]      = (__bf16)(o0[j] * inv);
    y2[((size_t)(b * TSEQ) + row) * EDIM + h * HDIM + wn + 16 + lr] = (__bf16)(o1[j] * inv);
  }
}

// ---------------------------------------------------------------- launcher
extern "C" void kernel_launch(void* const* d_in, const int* in_sizes, int n_in,
                              void* d_out, int out_size, void* d_ws, size_t ws_size,
                              hipStream_t stream) {
  const int*   tokens  = (const int*)d_in[0];
  const float* emb     = (const float*)d_in[1];
  const float* Wqkv    = (const float*)d_in[2];
  const float* bqkv    = (const float*)d_in[3];
  const float* Wo      = (const float*)d_in[4];
  const float* bo      = (const float*)d_in[5];
  const float* W1      = (const float*)d_in[6];
  const float* b1      = (const float*)d_in[7];
  const float* W3      = (const float*)d_in[8];
  const float* b3      = (const float*)d_in[9];
  const float* W2w     = (const float*)d_in[10];
  const float* b2      = (const float*)d_in[11];
  const float* g_mha   = (const float*)d_in[12];
  const float* g_ff    = (const float*)d_in[13];
  const float* g_final = (const float*)d_in[14];
  const float* Wout    = (const float*)d_in[15];
  const float* bout    = (const float*)d_in[16];
  float* out = (float*)d_out;

  char* base = (char*)d_ws;
  size_t off = 0;
  auto alloc = [&](size_t bytes) { char* p = base + off; off = (off + bytes + 255) & ~(size_t)255; return p; };
  float*  x    = (float*)alloc(4u << 20);
  float*  part = (float*)alloc(2048);
  __bf16* ybf  = (__bf16*)alloc(2u << 20);
  __bf16* qbf  = (__bf16*)alloc(2u << 20);
  __bf16* kbf  = (__bf16*)alloc(2u << 20);
  __bf16* vbT  = (__bf16*)alloc(2u << 20);
  __bf16* y2bf = (__bf16*)alloc(2u << 20);
  __bf16* ubf  = (__bf16*)alloc((size_t)MTOK * DPAD * 2);
  float*  pbuf = (float*)alloc((size_t)4 * NELEM * 4);
  __bf16* WoutT = (__bf16*)alloc((size_t)8192 * 1024 * 2);
  __bf16* qkvT = (__bf16*)alloc((size_t)NLAYER * 3072 * 1024 * 2);
  __bf16* woT  = (__bf16*)alloc((size_t)NLAYER * 1024 * 1024 * 2);
  __bf16* w1T  = (__bf16*)alloc((size_t)NLAYER * DPAD * 1024 * 2);
  __bf16* w3T  = (__bf16*)alloc((size_t)NLAYER * DPAD * 1024 * 2);
  __bf16* w2T  = (__bf16*)alloc((size_t)NLAYER * 1024 * DPAD * 2);

  k_embed<<<MTOK, 256, 0, stream>>>(tokens, emb, x);
  k_convAll<<<NLAYER * 3088, 256, 0, stream>>>(Wqkv, Wo, W1, W3, W2w,
                                               g_mha, g_ff,
                                               qkvT, woT, w1T, w3T, w2T);
  k_convH<<<2048, 256, 0, stream>>>(Wout, g_final, WoutT);

  const float* pend_bias = nullptr;
  for (int l = 0; l < NLAYER; ++l) {
    // --- MHA ---
    k_red1f<<<256, 256, 0, stream>>>(x, pend_bias ? pbuf : nullptr, 4, pend_bias,
                                     part, ybf);
    mm<64, 0, 1><<<dim3(48, 8, 1), 256, 0, stream>>>(
        ybf, qkvT + (size_t)l * 3072 * 1024, nullptr,
        bqkv + (size_t)l * 3 * EDIM, nullptr, part,
        nullptr, nullptr, qbf, kbf, vbT, 3072, 1024, 1024, 1024);
    k_flash<<<dim3(16, 32), 256, 0, stream>>>(qbf, kbf, vbT, y2bf);
    mm<64, 1, 0><<<dim3(16, 8, 4), 256, 0, stream>>>(
        y2bf, woT + (size_t)l * 1024 * 1024, nullptr,
        nullptr, nullptr, nullptr,
        pbuf, nullptr, nullptr, nullptr, nullptr, 1024, 1024, 1024, 1024);
    // --- SwiGLU FFN ---
    k_red1f<<<256, 256, 0, stream>>>(x, pbuf, 4, bo + (size_t)l * EDIM, part, ybf);
    mm<64, 2, 1><<<dim3(43, 8, 1), 256, 0, stream>>>(
        ybf, w1T + (size_t)l * DPAD * 1024, w3T + (size_t)l * DPAD * 1024,
        b1 + (size_t)l * DFFDIM, b3 + (size_t)l * DFFDIM, part,
        nullptr, ubf, nullptr, nullptr, nullptr, DFFDIM, 1024, 1024, 1024);
    mm<64, 1, 0><<<dim3(16, 8, 4), 256, 0, stream>>>(
        ubf, w2T + (size_t)l * 1024 * DPAD, nullptr,
        nullptr, nullptr, nullptr,
        pbuf, nullptr, nullptr, nullptr, nullptr, 1024, DPAD, DPAD, DPAD);
    pend_bias = b2 + (size_t)l * EDIM;
  }

  // --- final RMS + vocab head ---
  k_red1f<<<256, 256, 0, stream>>>(x, pbuf, 4, pend_bias, part, ybf);
  mm<128, 3, 1><<<dim3(64, 8, 1), 256, 0, stream>>>(
      ybf, WoutT, nullptr, bout, nullptr, part,
      out, nullptr, nullptr, nullptr, nullptr, VOCAB, 1024, 1024, 1024);
}